// Round 1
// baseline (120498.254 us; speedup 1.0000x reference)
//
#include <hip/hip_runtime.h>
#include <hip/hip_bf16.h>
#include <math.h>

// Problem constants (fixed by the reference)
#define B_  32
#define C_  64
#define T_  2048
#define H_  1024
#define LEAK 0.9f

// ---------------------------------------------------------------------------
// Kernel 1: x_proj[b,h,t] = b[h] + sum_c x[b,c,t] * W_in[h,c]
// written directly into d_out in (B,H,T) layout (the output layout), to be
// overwritten in-place by the recurrence kernel.
// grid: (T/256, H, B), block: 256
// ---------------------------------------------------------------------------
__global__ void esn_xproj_kernel(const float* __restrict__ x,
                                 const float* __restrict__ W_in,
                                 const float* __restrict__ bias,
                                 float* __restrict__ out) {
    int t = blockIdx.x * 256 + threadIdx.x;
    int h = blockIdx.y;
    int b = blockIdx.z;
    const float* xb = x + (size_t)b * C_ * T_;
    const float* wrow = W_in + (size_t)h * C_;
    float acc = bias[h];
#pragma unroll 8
    for (int c = 0; c < C_; ++c) {
        acc = fmaf(xb[(size_t)c * T_ + t], wrow[c], acc);
    }
    out[(size_t)b * H_ * T_ + (size_t)h * T_ + t] = acc;
}

// ---------------------------------------------------------------------------
// Kernel 2: sequential recurrence, one workgroup per batch element (no
// cross-workgroup dependencies -> no grid sync needed).
//   h_{t+1}[i] = 0.1*h_t[i] + 0.9*tanh(xp[t,i] + sum_j h_t[j]*W_res[i,j])
// 1024 threads = 16 waves. Each wave computes 64 output rows per step:
// row i's dot product is spread across the 64 lanes with coalesced float4
// reads of W_res, reduced with shfl_xor.
// h state ping-pongs in LDS. States overwrite x_proj in d_out.
// ---------------------------------------------------------------------------
__global__ __launch_bounds__(1024, 1) void esn_recurrence_kernel(
        const float* __restrict__ W_res,
        float* __restrict__ out) {
    __shared__ float hbuf[2][H_];

    const int b    = blockIdx.x;
    const int tid  = threadIdx.x;
    const int wave = tid >> 6;   // 0..15
    const int lane = tid & 63;   // 0..63

    hbuf[0][tid] = 0.0f;
    __syncthreads();

    float* outb = out + (size_t)b * H_ * T_;
    int cur = 0;

    for (int t = 0; t < T_; ++t) {
        const float* __restrict__ h = hbuf[cur];
        float* __restrict__ hn = hbuf[cur ^ 1];

        // each wave handles rows i = wave + 16*o, o = 0..63
        for (int o = 0; o < 64; ++o) {
            const int i = (o << 4) + wave;
            const float4* __restrict__ wrow =
                reinterpret_cast<const float4*>(W_res + (size_t)i * H_);
            float acc = 0.0f;
#pragma unroll
            for (int k = 0; k < 4; ++k) {
                // lanes read a contiguous 1KB segment: coalesced
                float4 wv = wrow[k * 64 + lane];
                float4 hv = *reinterpret_cast<const float4*>(
                    &h[k * 256 + lane * 4]);
                acc = fmaf(wv.x, hv.x, acc);
                acc = fmaf(wv.y, hv.y, acc);
                acc = fmaf(wv.z, hv.z, acc);
                acc = fmaf(wv.w, hv.w, acc);
            }
            // butterfly reduce across 64 lanes
#pragma unroll
            for (int s = 32; s > 0; s >>= 1) {
                acc += __shfl_xor(acc, s);
            }
            if (lane == 0) {
                float xp  = outb[(size_t)i * T_ + t];   // x_proj (pre-staged)
                float pre = tanhf(xp + acc);
                float hv  = fmaf(1.0f - LEAK, h[i], LEAK * pre);
                hn[i] = hv;
                outb[(size_t)i * T_ + t] = hv;          // overwrite with state
            }
        }
        __syncthreads();
        cur ^= 1;
    }
}

extern "C" void kernel_launch(void* const* d_in, const int* in_sizes, int n_in,
                              void* d_out, int out_size, void* d_ws, size_t ws_size,
                              hipStream_t stream) {
    const float* x     = (const float*)d_in[0];   // (B, C, T)
    const float* W_in  = (const float*)d_in[1];   // (H, C)
    const float* W_res = (const float*)d_in[2];   // (H, H)
    const float* bias  = (const float*)d_in[3];   // (H,)
    float* out = (float*)d_out;                   // (B, H, T)

    // Stage 1: x_proj into d_out (B,H,T layout)
    dim3 g1(T_ / 256, H_, B_);
    esn_xproj_kernel<<<g1, 256, 0, stream>>>(x, W_in, bias, out);

    // Stage 2: sequential recurrence, one WG per batch
    esn_recurrence_kernel<<<B_, 1024, 0, stream>>>(W_res, out);
}

// Round 2
// 114471.570 us; speedup vs baseline: 1.0526x; 1.0526x over previous
//
#include <hip/hip_runtime.h>
#include <math.h>

// Problem constants (fixed by the reference)
#define B_  32
#define C_  64
#define T_  2048
#define H_  1024

// Recurrence decomposition
#define NGROUP 8     // batch groups (sync domains)
#define BPG    4     // batches per group
#define NSLICE 32    // WGs per group (row slices)
#define ROWS   32    // rows of W_res per WG
#define NWG    (NGROUP * NSLICE)   // 256 workgroups == 256 CUs -> co-resident
#define NTHR   256

// d_ws layout:
//   bytes [0, 4096)        : unsigned counters, group g at cnt[g*32] (128B apart)
//   bytes [4096, 4096+256K): float hbuf[2][B_][H_]  (ping-pong h exchange)

// ---------------------------------------------------------------------------
// Init: zero barrier counters and h0 (must happen every launch/replay)
// grid 256 x 256 threads = 65536 = 2*B_*H_ exactly
// ---------------------------------------------------------------------------
__global__ void esn_init_kernel(unsigned* __restrict__ cnt,
                                float* __restrict__ hbuf) {
    int i = blockIdx.x * blockDim.x + threadIdx.x;
    if (i < NGROUP * 32) cnt[i] = 0u;
    hbuf[i] = 0.0f;   // i in [0, 65536) == 2*B_*H_
}

// ---------------------------------------------------------------------------
// x_proj[b,h,t] = bias[h] + sum_c x[b,c,t] * W_in[h,c], written into d_out
// (B,H,T) layout. Block: 256 t's x 8 h rows x 1 batch. x tile staged in LDS
// in two c-halves (32KB); W_in reads are wave-uniform -> scalar loads.
// grid: (T/256, H/8, B)
// ---------------------------------------------------------------------------
__global__ __launch_bounds__(256) void esn_xproj_kernel(
        const float* __restrict__ x,
        const float* __restrict__ W_in,
        const float* __restrict__ bias,
        float* __restrict__ out) {
    __shared__ float xs[32 * 256];
    const int tid = threadIdx.x;
    const int t0  = blockIdx.x * 256;
    const int h0  = blockIdx.y * 8;
    const int b   = blockIdx.z;
    const float* xb = x + (size_t)b * C_ * T_ + t0;

    float acc[8];
#pragma unroll
    for (int h = 0; h < 8; ++h) acc[h] = 0.0f;

    for (int ch = 0; ch < 2; ++ch) {
        // stage x[b][ch*32 .. ch*32+32)[t0..t0+256) -> LDS (coalesced float4)
        for (int idx = tid; idx < 32 * 64; idx += 256) {
            const int c  = idx >> 6;
            const int t4 = idx & 63;
            float4 v = *(const float4*)(xb + (size_t)(ch * 32 + c) * T_ + t4 * 4);
            *(float4*)(&xs[c * 256 + t4 * 4]) = v;
        }
        __syncthreads();
        for (int c = 0; c < 32; ++c) {
            const float xv = xs[c * 256 + tid];   // stride-1: conflict-free
#pragma unroll
            for (int h = 0; h < 8; ++h)           // uniform address -> s_load
                acc[h] = fmaf(xv, W_in[(size_t)(h0 + h) * C_ + ch * 32 + c], acc[h]);
        }
        __syncthreads();
    }

    float* ob = out + (size_t)b * H_ * T_ + t0 + tid;
#pragma unroll
    for (int h = 0; h < 8; ++h)
        ob[(size_t)(h0 + h) * T_] = acc[h] + bias[h0 + h];
}

// ---------------------------------------------------------------------------
// Recurrence. WG(wg): group g = wg/32 (batches g*4..g*4+3), slice s = wg%32
// (rows s*32..s*32+31). Each thread owns 128 W_res weights IN REGISTERS for
// the whole scan: thread (rl=tid/8, jg=tid%8) holds W_res[s*32+rl][jg*128+k],
// k=0..127 as 32 float4s. Per step:
//   load h (4 batches) -> LDS (padded 132-float slots, conflict-free b128
//   reads with 8-lane broadcast), dot with register weights, 3-level
//   shfl_xor reduce over the 8 j-lanes, lanes jg<4 finalize batch jg
//   (tanh/leak), write h_new to ping-pong global buffer + d_out, then
//   device-scope barrier among the 32 WGs of the group.
// ---------------------------------------------------------------------------
__global__ __launch_bounds__(NTHR, 1) void esn_recur_kernel(
        const float* __restrict__ W_res,
        float* __restrict__ out,
        unsigned* __restrict__ cnt,
        float* __restrict__ hbuf) {
    const int wg  = blockIdx.x;
    const int g   = wg >> 5;
    const int s   = wg & 31;
    const int tid = threadIdx.x;
    const int rl  = tid >> 3;          // 0..31 local row
    const int jg  = tid & 7;           // 0..7  j-chunk
    const int row = s * ROWS + rl;     // global row
    const int b0  = g * BPG;

    // ---- persistent register weights: 32 x float4 = 128 VGPRs ----
    float4 w4[32];
    {
        const float4* wr = (const float4*)(W_res + (size_t)row * H_) + jg * 32;
#pragma unroll
        for (int k = 0; k < 32; ++k) w4[k] = wr[k];
    }

    // padded h tiles: slot stride 132 floats => ds_read_b128 conflict-free
    __shared__ float hl[BPG][8 * 132];

    unsigned* mycnt = &cnt[g * 32];
    const int fjg  = tid >> 5;          // (tid*4)/128
    const int foff = (tid << 2) & 127;

    for (int t = 0; t < T_; ++t) {
        const int p = t & 1;

        // (A) global h -> LDS (coalesced float4 per batch)
#pragma unroll
        for (int b = 0; b < BPG; ++b) {
            float4 v = *(const float4*)(hbuf + (size_t)(p * B_ + b0 + b) * H_ + (tid << 2));
            *(float4*)(&hl[b][fjg * 132 + foff]) = v;
        }
        __syncthreads();

        // (C) dot products: 32 k-chunks x 4 batches, weights from registers
        float4 av[BPG];
        const float* hp[BPG];
#pragma unroll
        for (int b = 0; b < BPG; ++b) {
            av[b] = make_float4(0.f, 0.f, 0.f, 0.f);
            hp[b] = &hl[b][jg * 132];
        }
#pragma unroll
        for (int k = 0; k < 32; ++k) {
            const float4 w = w4[k];
#pragma unroll
            for (int b = 0; b < BPG; ++b) {
                const float4 hv = *(const float4*)(hp[b] + 4 * k);
                av[b].x = fmaf(w.x, hv.x, av[b].x);
                av[b].y = fmaf(w.y, hv.y, av[b].y);
                av[b].z = fmaf(w.z, hv.z, av[b].z);
                av[b].w = fmaf(w.w, hv.w, av[b].w);
            }
        }
        float asum[BPG];
#pragma unroll
        for (int b = 0; b < BPG; ++b) {
            asum[b] = (av[b].x + av[b].y) + (av[b].z + av[b].w);
#pragma unroll
            for (int m = 1; m <= 4; m <<= 1)
                asum[b] += __shfl_xor(asum[b], m);
        }

        // (D) finalize: lane jg<4 handles batch b0+jg for this row
        if (jg < BPG) {
            const int b = b0 + jg;
            const float sum = (jg == 0) ? asum[0] : (jg == 1) ? asum[1]
                            : (jg == 2) ? asum[2] : asum[3];
            float* op = out + ((size_t)b * H_ + row) * T_ + t;
            const float xp   = *op;                       // staged x_proj
            const float pre  = tanhf(xp + sum);
            const float hold = hl[jg][(row >> 7) * 132 + (row & 127)];
            const float hnew = fmaf(0.1f, hold, 0.9f * pre);
            *op = hnew;                                   // state out
            hbuf[(size_t)(((t + 1) & 1) * B_ + b) * H_ + row] = hnew;
        }

        // (E) inter-WG barrier for this group (skip after last step)
        if (t + 1 < T_) {
            __threadfence();
            __syncthreads();
            if (tid == 0) {
                __hip_atomic_fetch_add(mycnt, 1u, __ATOMIC_RELEASE,
                                       __HIP_MEMORY_SCOPE_AGENT);
                const unsigned target = (unsigned)NSLICE * (unsigned)(t + 1);
                while (__hip_atomic_load(mycnt, __ATOMIC_ACQUIRE,
                                         __HIP_MEMORY_SCOPE_AGENT) < target) {
                    __builtin_amdgcn_s_sleep(1);
                }
            }
            __syncthreads();
            __threadfence();
        }
    }
}

extern "C" void kernel_launch(void* const* d_in, const int* in_sizes, int n_in,
                              void* d_out, int out_size, void* d_ws, size_t ws_size,
                              hipStream_t stream) {
    const float* x     = (const float*)d_in[0];   // (B, C, T)
    const float* W_in  = (const float*)d_in[1];   // (H, C)
    const float* W_res = (const float*)d_in[2];   // (H, H)
    const float* bias  = (const float*)d_in[3];   // (H,)
    float* out = (float*)d_out;                   // (B, H, T)

    unsigned* cnt  = (unsigned*)d_ws;
    float*    hbuf = (float*)((char*)d_ws + 4096);

    // 1) zero counters + h0 (every call: graph replays must be identical)
    esn_init_kernel<<<256, 256, 0, stream>>>(cnt, hbuf);

    // 2) x_proj into d_out (B,H,T layout)
    dim3 g1(T_ / 256, H_ / 8, B_);
    esn_xproj_kernel<<<g1, 256, 0, stream>>>(x, W_in, bias, out);

    // 3) recurrence: 256 WGs (8 groups x 32 slices), weights in registers
    esn_recur_kernel<<<NWG, NTHR, 0, stream>>>(W_res, out, cnt, hbuf);
}

// Round 5
// 26613.559 us; speedup vs baseline: 4.5277x; 4.3012x over previous
//
#include <hip/hip_runtime.h>
#include <math.h>

// Problem constants (fixed by the reference)
#define B_  32
#define C_  64
#define T_  2048
#define H_  1024

// Recurrence decomposition: 16 groups x 2 batches; 16 WGs (slices) per group
#define NGROUP 16
#define BPG    2
#define NSLICE 16
#define ROWS   64                    // H / NSLICE
#define NWG    (NGROUP * NSLICE)     // 256 WGs == 256 CUs, 1/CU -> co-resident
#define NTHR   512
#define CHUNK  68                    // padded LDS chunk stride (64 + 4 floats)

// d_ws layout:
//   [0, 4096)          : unsigned flags[1024]  (flag[wg], grouped 16/group)
//   [4096, 4096+256KB) : float hbuf[2][B_][H_] (ping-pong h exchange)

__global__ void esn_init_kernel(unsigned* __restrict__ flags,
                                float* __restrict__ hbuf) {
    int i = blockIdx.x * blockDim.x + threadIdx.x;
    if (i < 1024) flags[i] = 0u;
    hbuf[i] = 0.0f;   // i in [0, 65536) == 2*B_*H_
}

// ---------------------------------------------------------------------------
// x_proj[b,h,t] = bias[h] + sum_c x[b,c,t] * W_in[h,c] -> d_out (B,H,T)
// ---------------------------------------------------------------------------
__global__ __launch_bounds__(256) void esn_xproj_kernel(
        const float* __restrict__ x,
        const float* __restrict__ W_in,
        const float* __restrict__ bias,
        float* __restrict__ out) {
    __shared__ float xs[32 * 256];
    const int tid = threadIdx.x;
    const int t0  = blockIdx.x * 256;
    const int h0  = blockIdx.y * 8;
    const int b   = blockIdx.z;
    const float* xb = x + (size_t)b * C_ * T_ + t0;

    float acc[8];
#pragma unroll
    for (int h = 0; h < 8; ++h) acc[h] = 0.0f;

    for (int ch = 0; ch < 2; ++ch) {
        for (int idx = tid; idx < 32 * 64; idx += 256) {
            const int c  = idx >> 6;
            const int t4 = idx & 63;
            float4 v = *(const float4*)(xb + (size_t)(ch * 32 + c) * T_ + t4 * 4);
            *(float4*)(&xs[c * 256 + t4 * 4]) = v;
        }
        __syncthreads();
        for (int c = 0; c < 32; ++c) {
            const float xv = xs[c * 256 + tid];
#pragma unroll
            for (int h = 0; h < 8; ++h)
                acc[h] = fmaf(xv, W_in[(size_t)(h0 + h) * C_ + ch * 32 + c], acc[h]);
        }
        __syncthreads();
    }

    float* ob = out + (size_t)b * H_ * T_ + t0 + tid;
#pragma unroll
    for (int h = 0; h < 8; ++h)
        ob[(size_t)(h0 + h) * T_] = acc[h] + bias[h0 + h];
}

// ---------------------------------------------------------------------------
// Recurrence. WG wg: group g = wg/16 (batches g*2, g*2+1), slice s = wg%16
// (rows s*64 .. s*64+63). Thread (cg = lane&15, rt = wave*4 + lane/16) holds
// W_res[s*64+rt*2 + {0,1}][cg*64 .. cg*64+63] loaded to registers BEFORE the
// t-loop (no __restrict__ anywhere -> in-loop reload of W_res would be
// illegal under possible aliasing with the stores -> values stay register/
// AGPR-resident).
// Sync protocol (the round-4 bug fix): per step,
//   writer side: __syncthreads() (all waves drain vmcnt: write-through h
//     stores complete) then tid0 posts flag with a RELEASE store
//     (buffer_wbl2 sc1 + vmcnt wait + sc0sc1 store);
//   reader side: wave 0 polls peer flags RELAXED, then ONE __threadfence()
//     (acquire: buffer_inv sc1) before anyone reads the new h plane.
// All in-loop global stores are write-through relaxed atomics so the L2
// stays clean and the wbl2 in the release store is cheap.
// ---------------------------------------------------------------------------
__global__ __launch_bounds__(NTHR, 2) void esn_recur_kernel(
        const float* W_res,
        float* out,
        unsigned* flags,
        float* hbuf) {
    const int wg   = blockIdx.x;
    const int g    = wg >> 4;
    const int s    = wg & 15;
    const int tid  = threadIdx.x;
    const int wave = tid >> 6;
    const int lane = tid & 63;
    const int cg   = lane & 15;                 // col-group: cols cg*64..+63
    const int rt   = (wave << 2) + (lane >> 4); // 0..31 row-pair index
    const int row0 = s * ROWS + rt * 2;
    const int b0   = g * BPG;

    // ---- persistent register weights: 2 rows x 16 float4 ----
    float4 w0[16], w1[16];
    {
        const float4* p0 = (const float4*)(W_res + (size_t)row0 * H_) + (cg << 4);
        const float4* p1 = (const float4*)(W_res + (size_t)(row0 + 1) * H_) + (cg << 4);
#pragma unroll
        for (int k = 0; k < 16; ++k) { w0[k] = p0[k]; w1[k] = p1[k]; }
    }

    // h tiles in LDS, padded chunks: col c of batch b at hl[b][(c/64)*68 + c%64]
    __shared__ __align__(16) float hl[BPG][16 * CHUNK];

    // h-fill role: thread loads 4 consecutive h floats
    const int fb = tid >> 8;                 // batch 0/1
    const int fc = (tid << 2) & 1023;        // col base
    float* hlw = &hl[fb][(fc >> 6) * CHUNK + (fc & 63)];

    // finalize role: lanes cg<4 own (batch cg&1, row row0 + (cg>>1)&1)
    const bool fin  = (cg < 4);
    const int  fbat = cg & 1;
    const int  frow = row0 + ((cg >> 1) & 1);
    float* op = out + ((size_t)(b0 + fbat) * H_ + frow) * (size_t)T_;

    float xp = fin ? op[0] : 0.0f;           // x_proj for step 0 (plain cached)

    for (int t = 0; t < T_; ++t) {
        const int p = t & 1;

        // (A) h from coherent point -> LDS (relaxed agent atomics)
        {
            float* hb = hbuf + ((size_t)p * B_ + b0 + fb) * H_ + fc;
            float4 v;
            v.x = __hip_atomic_load(hb + 0, __ATOMIC_RELAXED, __HIP_MEMORY_SCOPE_AGENT);
            v.y = __hip_atomic_load(hb + 1, __ATOMIC_RELAXED, __HIP_MEMORY_SCOPE_AGENT);
            v.z = __hip_atomic_load(hb + 2, __ATOMIC_RELAXED, __HIP_MEMORY_SCOPE_AGENT);
            v.w = __hip_atomic_load(hb + 3, __ATOMIC_RELAXED, __HIP_MEMORY_SCOPE_AGENT);
            *(float4*)hlw = v;
        }
        __syncthreads();
        __builtin_amdgcn_sched_barrier(0);

        // prefetch next step's x_proj (latency hidden under the dot phase)
        float xp_next = 0.0f;
        if (fin && t + 1 < T_) xp_next = op[t + 1];

        // (B) dot: 2 rows x 64 cols x 2 batches, weights from registers
        float s00 = 0.f, s01 = 0.f, s10 = 0.f, s11 = 0.f;  // s[r][b]
        const float* h0 = &hl[0][cg * CHUNK];
        const float* h1 = &hl[1][cg * CHUNK];
#pragma unroll
        for (int k = 0; k < 16; ++k) {
            const float4 ha  = *(const float4*)(h0 + 4 * k);
            const float4 hb4 = *(const float4*)(h1 + 4 * k);
            const float4 u = w0[k], v = w1[k];
            s00 = fmaf(u.x, ha.x, s00);  s00 = fmaf(u.y, ha.y, s00);
            s00 = fmaf(u.z, ha.z, s00);  s00 = fmaf(u.w, ha.w, s00);
            s10 = fmaf(v.x, ha.x, s10);  s10 = fmaf(v.y, ha.y, s10);
            s10 = fmaf(v.z, ha.z, s10);  s10 = fmaf(v.w, ha.w, s10);
            s01 = fmaf(u.x, hb4.x, s01); s01 = fmaf(u.y, hb4.y, s01);
            s01 = fmaf(u.z, hb4.z, s01); s01 = fmaf(u.w, hb4.w, s01);
            s11 = fmaf(v.x, hb4.x, s11); s11 = fmaf(v.y, hb4.y, s11);
            s11 = fmaf(v.w, hb4.w, s11); s11 = fmaf(v.z, hb4.z, s11);
        }
        // (C) reduce over the 16 cg lanes
#pragma unroll
        for (int m = 1; m <= 8; m <<= 1) {
            s00 += __shfl_xor(s00, m);
            s01 += __shfl_xor(s01, m);
            s10 += __shfl_xor(s10, m);
            s11 += __shfl_xor(s11, m);
        }

        // (D) finalize: cg 0->(r0,b0)=s00, 1->(r0,b1)=s01, 2->(r1,b0)=s10, 3->s11
        if (fin) {
            const float sum = (cg == 0) ? s00 : (cg == 1) ? s01
                            : (cg == 2) ? s10 : s11;
            const float pre  = tanhf(xp + sum);
            const float hold = hl[fbat][(frow >> 6) * CHUNK + (frow & 63)];
            const float hnew = fmaf(0.1f, hold, 0.9f * pre);
            // state out: write-through (keeps L2 clean for the release wbl2)
            __hip_atomic_store(op + t, hnew,
                               __ATOMIC_RELAXED, __HIP_MEMORY_SCOPE_AGENT);
            __hip_atomic_store(
                hbuf + ((size_t)((t + 1) & 1) * B_ + b0 + fbat) * H_ + frow,
                hnew, __ATOMIC_RELAXED, __HIP_MEMORY_SCOPE_AGENT);
        }
        xp = xp_next;

        // (E) flag barrier among the 16 WGs of this group
        if (t + 1 < T_) {
            __syncthreads();   // all waves drain vmcnt: h stores complete
            if (tid == 0)
                __hip_atomic_store(&flags[wg], (unsigned)(t + 1),
                                   __ATOMIC_RELEASE, __HIP_MEMORY_SCOPE_AGENT);
            if (wave == 0) {
                const unsigned tgt = (unsigned)(t + 1);
                unsigned v = 0xFFFFFFFFu;
                for (;;) {
                    if (lane < NSLICE)
                        v = __hip_atomic_load(&flags[(g << 4) + lane],
                                              __ATOMIC_RELAXED,
                                              __HIP_MEMORY_SCOPE_AGENT);
                    if (!__any(v < tgt)) break;
                    __builtin_amdgcn_s_sleep(2);
                }
                __threadfence();   // ACQUIRE: buffer_inv sc1 before h reads
            }
            __syncthreads();
            __builtin_amdgcn_sched_barrier(0);
        }
    }
}

extern "C" void kernel_launch(void* const* d_in, const int* in_sizes, int n_in,
                              void* d_out, int out_size, void* d_ws, size_t ws_size,
                              hipStream_t stream) {
    const float* x     = (const float*)d_in[0];   // (B, C, T)
    const float* W_in  = (const float*)d_in[1];   // (H, C)
    const float* W_res = (const float*)d_in[2];   // (H, H)
    const float* bias  = (const float*)d_in[3];   // (H,)
    float* out = (float*)d_out;                   // (B, H, T)

    unsigned* flags = (unsigned*)d_ws;
    float*    hbuf  = (float*)((char*)d_ws + 4096);

    esn_init_kernel<<<256, 256, 0, stream>>>(flags, hbuf);

    dim3 g1(T_ / 256, H_ / 8, B_);
    esn_xproj_kernel<<<g1, 256, 0, stream>>>(x, W_in, bias, out);

    esn_recur_kernel<<<NWG, NTHR, 0, stream>>>(W_res, out, flags, hbuf);
}

// Round 6
// 6650.714 us; speedup vs baseline: 18.1181x; 4.0016x over previous
//
#include <hip/hip_runtime.h>
#include <math.h>

// Problem constants (fixed by the reference)
#define B_  32
#define C_  64
#define T_  2048
#define H_  1024

// Recurrence decomposition: 16 groups x 2 batches; 16 WGs (slices) per group
#define NGROUP 16
#define BPG    2
#define NSLICE 16
#define ROWS   64                    // H / NSLICE
#define NWG    (NGROUP * NSLICE)     // 256 WGs == 256 CUs, 1/CU -> co-resident
#define NTHR   512
#define CHUNK  68                    // padded LDS chunk stride (64 + 4 floats)

// d_ws layout:
//   [0, 4096)          : unsigned cnt[1024]; group g's barrier counter at
//                        cnt[g*32] (128B apart). cnt[512] = sink dump (unused)
//   [4096, 4096+256KB) : float hbuf[2][B_][H_] (ping-pong h exchange)

__global__ void esn_init_kernel(unsigned* __restrict__ cnt,
                                float* __restrict__ hbuf) {
    int i = blockIdx.x * blockDim.x + threadIdx.x;
    if (i < 1024) cnt[i] = 0u;
    hbuf[i] = 0.0f;   // i in [0, 65536) == 2*B_*H_
}

// ---------------------------------------------------------------------------
// x_proj[b,h,t] = bias[h] + sum_c x[b,c,t] * W_in[h,c] -> d_out (B,H,T)
// ---------------------------------------------------------------------------
__global__ __launch_bounds__(256) void esn_xproj_kernel(
        const float* __restrict__ x,
        const float* __restrict__ W_in,
        const float* __restrict__ bias,
        float* __restrict__ out) {
    __shared__ float xs[32 * 256];
    const int tid = threadIdx.x;
    const int t0  = blockIdx.x * 256;
    const int h0  = blockIdx.y * 8;
    const int b   = blockIdx.z;
    const float* xb = x + (size_t)b * C_ * T_ + t0;

    float acc[8];
#pragma unroll
    for (int h = 0; h < 8; ++h) acc[h] = 0.0f;

    for (int ch = 0; ch < 2; ++ch) {
        for (int idx = tid; idx < 32 * 64; idx += 256) {
            const int c  = idx >> 6;
            const int t4 = idx & 63;
            float4 v = *(const float4*)(xb + (size_t)(ch * 32 + c) * T_ + t4 * 4);
            *(float4*)(&xs[c * 256 + t4 * 4]) = v;
        }
        __syncthreads();
        for (int c = 0; c < 32; ++c) {
            const float xv = xs[c * 256 + tid];
#pragma unroll
            for (int h = 0; h < 8; ++h)
                acc[h] = fmaf(xv, W_in[(size_t)(h0 + h) * C_ + ch * 32 + c], acc[h]);
        }
        __syncthreads();
    }

    float* ob = out + (size_t)b * H_ * T_ + t0 + tid;
#pragma unroll
    for (int h = 0; h < 8; ++h)
        ob[(size_t)(h0 + h) * T_] = acc[h] + bias[h0 + h];
}

// ---------------------------------------------------------------------------
// Recurrence. WG wg: group g = wg/16 (batches g*2, g*2+1), slice s = wg%16
// (rows s*64..s*64+63). Thread (cg = lane&15, rt = wave*4 + lane/16) holds
// W_res[s*64+rt*2 + {0,1}][cg*64..cg*64+63] loaded to registers BEFORE the
// t-loop (no __restrict__ -> in-loop reload illegal under possible aliasing
// -> values stay in the unified VGPR/AGPR file; verified by round-5 pass).
//
// Cross-WG exchange (round-6 change): ALL cross-WG data moves via relaxed
// AGENT-scope atomic RMWs, which execute at the LLC (the device coherence
// point) -- no stale-cache hazard, therefore NO release wbl2, NO acquire
// buffer_inv anywhere in the loop (those were ~10us/step in round 5).
//   h write : returning u64 atomic_exchange (row pair); return XOR'd into a
//             live sink so the swap stays the RETURNING form (vmcnt ack =>
//             executed at LLC).
//   h read  : u64 fetch_add(+0) -- reads the LLC copy directly.
//   barrier : monotone per-group counter; arrive = fetch_add(1) AFTER
//             __syncthreads() (vmcnt(0) drained => all swaps done at LLC);
//             tid0 polls fetch_add(0) until cnt >= 16*(t+1).
// out/xp traffic is plain cached loads/stores: with no invalidation the
// lines persist in L2 across steps.
// ---------------------------------------------------------------------------
__global__ __launch_bounds__(NTHR, 2) void esn_recur_kernel(
        const float* W_res,
        float* out,
        unsigned* cnt,
        float* hbuf) {
    const int wg   = blockIdx.x;
    const int g    = wg >> 4;
    const int s    = wg & 15;
    const int tid  = threadIdx.x;
    const int wave = tid >> 6;
    const int lane = tid & 63;
    const int cg   = lane & 15;                 // col-group: cols cg*64..+63
    const int rt   = (wave << 2) + (lane >> 4); // 0..31 row-pair index
    const int row0 = s * ROWS + rt * 2;
    const int b0   = g * BPG;

    unsigned long long* hb64 = (unsigned long long*)hbuf;

    // ---- persistent register weights: 2 rows x 16 float4 ----
    float4 w0[16], w1[16];
    {
        const float4* p0 = (const float4*)(W_res + (size_t)row0 * H_) + (cg << 4);
        const float4* p1 = (const float4*)(W_res + (size_t)(row0 + 1) * H_) + (cg << 4);
#pragma unroll
        for (int k = 0; k < 16; ++k) { w0[k] = p0[k]; w1[k] = p1[k]; }
    }

    // h tiles in LDS, padded chunks: col c of batch b at hl[b][(c/64)*68 + c%64]
    __shared__ __align__(16) float hl[BPG][16 * CHUNK];

    // h-fill role: thread loads 4 consecutive h floats (2 u64 RMWs)
    const int fb = tid >> 8;                 // batch 0/1
    const int fc = (tid << 2) & 1023;        // col base (multiple of 4)
    float* hlw = &hl[fb][(fc >> 6) * CHUNK + (fc & 63)];

    // finalize role: lanes cg<2 own batch b0+cg, rows (row0, row0+1)
    const bool fin  = (cg < BPG);
    const int  fbat = cg;                    // 0/1 (valid when fin)
    float* op0 = out + ((size_t)(b0 + (fin ? fbat : 0)) * H_ + row0) * (size_t)T_;
    float* op1 = op0 + T_;                   // next row, same batch

    float xp0 = fin ? op0[0] : 0.0f;         // x_proj for step 0
    float xp1 = fin ? op1[0] : 0.0f;

    unsigned long long sink = 0ull;
    unsigned* grpcnt = &cnt[g * 32];

    for (int t = 0; t < T_; ++t) {
        const int p = t & 1;

        // (A) h from LLC -> LDS via u64 fetch_add(+0) (always coherent)
        {
            const size_t i64 = (((size_t)p * B_ + b0 + fb) * H_ + fc) >> 1;
            unsigned long long q0 = __hip_atomic_fetch_add(
                hb64 + i64, 0ull, __ATOMIC_RELAXED, __HIP_MEMORY_SCOPE_AGENT);
            unsigned long long q1 = __hip_atomic_fetch_add(
                hb64 + i64 + 1, 0ull, __ATOMIC_RELAXED, __HIP_MEMORY_SCOPE_AGENT);
            float4 v = make_float4(__uint_as_float((unsigned)q0),
                                   __uint_as_float((unsigned)(q0 >> 32)),
                                   __uint_as_float((unsigned)q1),
                                   __uint_as_float((unsigned)(q1 >> 32)));
            *(float4*)hlw = v;
        }
        __syncthreads();
        __builtin_amdgcn_sched_barrier(0);

        // prefetch next step's x_proj (plain cached; lines persist in L2 now)
        float xp0n = 0.0f, xp1n = 0.0f;
        if (fin && t + 1 < T_) { xp0n = op0[t + 1]; xp1n = op1[t + 1]; }

        // (B) dot: 2 rows x 64 cols x 2 batches, weights from registers
        float s00 = 0.f, s01 = 0.f, s10 = 0.f, s11 = 0.f;  // s[row][batch]
        const float* h0 = &hl[0][cg * CHUNK];
        const float* h1 = &hl[1][cg * CHUNK];
#pragma unroll
        for (int k = 0; k < 16; ++k) {
            const float4 ha  = *(const float4*)(h0 + 4 * k);
            const float4 hb4 = *(const float4*)(h1 + 4 * k);
            const float4 u = w0[k], v = w1[k];
            s00 = fmaf(u.x, ha.x, s00);  s00 = fmaf(u.y, ha.y, s00);
            s00 = fmaf(u.z, ha.z, s00);  s00 = fmaf(u.w, ha.w, s00);
            s10 = fmaf(v.x, ha.x, s10);  s10 = fmaf(v.y, ha.y, s10);
            s10 = fmaf(v.z, ha.z, s10);  s10 = fmaf(v.w, ha.w, s10);
            s01 = fmaf(u.x, hb4.x, s01); s01 = fmaf(u.y, hb4.y, s01);
            s01 = fmaf(u.z, hb4.z, s01); s01 = fmaf(u.w, hb4.w, s01);
            s11 = fmaf(v.x, hb4.x, s11); s11 = fmaf(v.y, hb4.y, s11);
            s11 = fmaf(v.z, hb4.z, s11); s11 = fmaf(v.w, hb4.w, s11);
        }
        // (C) reduce over the 16 cg lanes
#pragma unroll
        for (int m = 1; m <= 8; m <<= 1) {
            s00 += __shfl_xor(s00, m);
            s01 += __shfl_xor(s01, m);
            s10 += __shfl_xor(s10, m);
            s11 += __shfl_xor(s11, m);
        }

        // (D) finalize: lane cg owns batch b0+cg, rows row0 & row0+1
        if (fin) {
            const float sA = fbat ? s01 : s00;   // row0
            const float sB = fbat ? s11 : s10;   // row0+1
            const float pre0 = tanhf(xp0 + sA);
            const float pre1 = tanhf(xp1 + sB);
            const float* hc = &hl[fbat][((row0 >> 6) * CHUNK) + (row0 & 63)];
            const float hn0 = fmaf(0.1f, hc[0], 0.9f * pre0);
            const float hn1 = fmaf(0.1f, hc[1], 0.9f * pre1);
            op0[t] = hn0;                         // plain cached output stores
            op1[t] = hn1;
            const unsigned long long pack =
                ((unsigned long long)__float_as_uint(hn1) << 32) |
                (unsigned long long)__float_as_uint(hn0);
            const size_t w64 =
                (((size_t)((t + 1) & 1) * B_ + b0 + fbat) * H_ + row0) >> 1;
            // RETURNING swap (sink keeps sc0): ack => executed at LLC
            sink ^= __hip_atomic_exchange(hb64 + w64, pack,
                                          __ATOMIC_RELAXED,
                                          __HIP_MEMORY_SCOPE_AGENT);
        }
        xp0 = xp0n;
        xp1 = xp1n;

        // (E) fence-free group barrier: monotone LLC counter
        if (t + 1 < T_) {
            __syncthreads();   // vmcnt(0): all swaps executed at LLC
            __builtin_amdgcn_sched_barrier(0);
            if (tid == 0) {
                __hip_atomic_fetch_add(grpcnt, 1u, __ATOMIC_RELAXED,
                                       __HIP_MEMORY_SCOPE_AGENT);
                const unsigned tgt = (unsigned)NSLICE * (unsigned)(t + 1);
                while (__hip_atomic_fetch_add(grpcnt, 0u, __ATOMIC_RELAXED,
                                              __HIP_MEMORY_SCOPE_AGENT) < tgt) {
                    __builtin_amdgcn_s_sleep(1);
                }
            }
            __syncthreads();
            __builtin_amdgcn_sched_barrier(0);
        }
    }

    // keep the swap returns live (forces the returning/sc0 form)
    if (sink == 0x9E3779B97F4A7C15ull && tid == 0) cnt[512] = 1u;
}

extern "C" void kernel_launch(void* const* d_in, const int* in_sizes, int n_in,
                              void* d_out, int out_size, void* d_ws, size_t ws_size,
                              hipStream_t stream) {
    const float* x     = (const float*)d_in[0];   // (B, C, T)
    const float* W_in  = (const float*)d_in[1];   // (H, C)
    const float* W_res = (const float*)d_in[2];   // (H, H)
    const float* bias  = (const float*)d_in[3];   // (H,)
    float* out = (float*)d_out;                   // (B, H, T)

    unsigned* cnt  = (unsigned*)d_ws;
    float*    hbuf = (float*)((char*)d_ws + 4096);

    esn_init_kernel<<<256, 256, 0, stream>>>(cnt, hbuf);

    dim3 g1(T_ / 256, H_ / 8, B_);
    esn_xproj_kernel<<<g1, 256, 0, stream>>>(x, W_in, bias, out);

    esn_recur_kernel<<<NWG, NTHR, 0, stream>>>(W_res, out, cnt, hbuf);
}